// Round 1
// baseline (660.596 us; speedup 1.0000x reference)
//
#include <hip/hip_runtime.h>
#include <cstdint>
#include <cstddef>

#define F_IN 128
#define HID 16

// ---------------- index-width detection ----------------
// If edge_index is int64 (little-endian, values < 2^31, non-negative), every
// odd 32-bit word of the first 64 entries is zero. For int32 random node ids
// in [0,100000), P(64 words all zero) ~ 1e-320. Flag: 1 = int64, 0 = int32.
__global__ void k_detect(const int* __restrict__ eidx, int* __restrict__ flag) {
    if (blockIdx.x == 0 && threadIdx.x == 0) {
        int all0 = 1;
        for (int i = 0; i < 64; ++i) {
            if (eidx[2 * i + 1] != 0) { all0 = 0; break; }
        }
        *flag = all0;
    }
}

__device__ __forceinline__ int ld_idx(const int* __restrict__ p, int e, int is64) {
    return is64 ? p[2 * e] : p[e];
}

// ---------------- degree (on A+I) ----------------
__global__ void k_deg(const int* __restrict__ eidx, int E,
                      const int* __restrict__ flag, float* __restrict__ deg) {
    int e = blockIdx.x * blockDim.x + threadIdx.x;
    if (e >= E) return;
    int is64 = *flag;
    const int* colp = eidx + ((size_t)E << is64);
    int c = ld_idx(colp, e, is64);
    atomicAdd(&deg[c], 1.0f);
}

__global__ void k_dinv(float* __restrict__ deg, int n) {
    int i = blockIdx.x * blockDim.x + threadIdx.x;
    if (i < n) deg[i] = rsqrtf(deg[i] + 1.0f);
}

// ---------------- h = x @ W1   [n,128] @ [128,16] ----------------
__launch_bounds__(256)
__global__ void k_gemm1(const float* __restrict__ x, const float* __restrict__ W1,
                        float* __restrict__ h, int n) {
    // W transposed into LDS with padded stride 132 so float4 reads avoid conflicts
    __shared__ float Wt[16 * 132];
    for (int i = threadIdx.x; i < F_IN * HID; i += 256) {
        int k = i >> 4, j = i & 15;
        Wt[j * 132 + k] = W1[i];
    }
    __syncthreads();
    int row = blockIdx.x * 16 + (threadIdx.x >> 4);
    int j = threadIdx.x & 15;
    if (row >= n) return;
    const float4* xr = (const float4*)(x + (size_t)row * F_IN);
    float acc = 0.f;
#pragma unroll
    for (int kk = 0; kk < 32; ++kk) {
        float4 xv = xr[kk];
        float4 wv = *(const float4*)&Wt[j * 132 + 4 * kk];
        acc += xv.x * wv.x + xv.y * wv.y + xv.z * wv.z + xv.w * wv.w;
    }
    h[(size_t)row * HID + j] = acc;
}

// ---------------- scatter aggregation: agg[c] += h[r] * dinv[r]*dinv[c] ----------------
__global__ void k_agg(const int* __restrict__ eidx, int E, const int* __restrict__ flag,
                      const float* __restrict__ h, const float* __restrict__ dinv,
                      float* __restrict__ agg) {
    int tid = blockIdx.x * blockDim.x + threadIdx.x;
    int e = tid >> 4;
    if (e >= E) return;
    int j = tid & 15;
    int is64 = *flag;
    const int* rowp = eidx;
    const int* colp = eidx + ((size_t)E << is64);
    int r = ld_idx(rowp, e, is64);
    int c = ld_idx(colp, e, is64);
    float nrm = dinv[r] * dinv[c];
    atomicAdd(&agg[(size_t)c * HID + j], h[(size_t)r * HID + j] * nrm);
}

// ---------------- out = relu(agg + h*dinv^2 + b) ----------------
__global__ void k_finish(const float* __restrict__ agg, const float* __restrict__ h,
                         const float* __restrict__ dinv, const float* __restrict__ b,
                         float* __restrict__ out, int n) {
    int tid = blockIdx.x * blockDim.x + threadIdx.x;
    int i = tid >> 4;
    if (i >= n) return;
    int j = tid & 15;
    float d = dinv[i];
    float val = agg[tid] + h[tid] * d * d + b[j];
    out[tid] = fmaxf(val, 0.f);
}

// ---------------- h2 = h1r @ W2   [n,16] @ [16,16] ----------------
__launch_bounds__(256)
__global__ void k_gemm2(const float* __restrict__ h, const float* __restrict__ W2,
                        float* __restrict__ out, int n) {
    __shared__ float Ws[16 * 16];
    if (threadIdx.x < 256) Ws[threadIdx.x] = W2[threadIdx.x];
    __syncthreads();
    int row = blockIdx.x * 16 + (threadIdx.x >> 4);
    int j = threadIdx.x & 15;
    if (row >= n) return;
    const float4* hp = (const float4*)(h + (size_t)row * HID);
    float4 h0 = hp[0], h1 = hp[1], h2 = hp[2], h3 = hp[3];
    float hv[16] = {h0.x, h0.y, h0.z, h0.w, h1.x, h1.y, h1.z, h1.w,
                    h2.x, h2.y, h2.z, h2.w, h3.x, h3.y, h3.z, h3.w};
    float acc = 0.f;
#pragma unroll
    for (int k = 0; k < 16; ++k) acc += hv[k] * Ws[k * 16 + j];
    out[(size_t)row * HID + j] = acc;
}

// ---------------- u = h @ fc1W[:16], v = h @ fc1W[16:] ----------------
__launch_bounds__(256)
__global__ void k_uv(const float* __restrict__ h, const float* __restrict__ fc1W,
                     float* __restrict__ u, float* __restrict__ v, int n) {
    __shared__ float Ws[32 * 16];
    for (int i = threadIdx.x; i < 512; i += 256) Ws[i] = fc1W[i];
    __syncthreads();
    int row = blockIdx.x * 16 + (threadIdx.x >> 4);
    int j = threadIdx.x & 15;
    if (row >= n) return;
    const float4* hp = (const float4*)(h + (size_t)row * HID);
    float4 h0 = hp[0], h1 = hp[1], h2 = hp[2], h3 = hp[3];
    float hv[16] = {h0.x, h0.y, h0.z, h0.w, h1.x, h1.y, h1.z, h1.w,
                    h2.x, h2.y, h2.z, h2.w, h3.x, h3.y, h3.z, h3.w};
    float au = 0.f, av = 0.f;
#pragma unroll
    for (int k = 0; k < 16; ++k) {
        au += hv[k] * Ws[k * 16 + j];
        av += hv[k] * Ws[(16 + k) * 16 + j];
    }
    u[(size_t)row * HID + j] = au;
    v[(size_t)row * HID + j] = av;
}

// ---------------- per-edge MLP + log_softmax ----------------
__launch_bounds__(256)
__global__ void k_edge(const int* __restrict__ eidx, int E, const int* __restrict__ flag,
                       const float* __restrict__ u, const float* __restrict__ v,
                       const float* __restrict__ fc1b, const float* __restrict__ fc2W,
                       const float* __restrict__ fc2b, float* __restrict__ out) {
    __shared__ float b1s[16], W2s[32], b2s[2];
    if (threadIdx.x < 16) b1s[threadIdx.x] = fc1b[threadIdx.x];
    if (threadIdx.x < 32) W2s[threadIdx.x] = fc2W[threadIdx.x];
    if (threadIdx.x < 2) b2s[threadIdx.x] = fc2b[threadIdx.x];
    __syncthreads();
    int e = blockIdx.x * blockDim.x + threadIdx.x;
    if (e >= E) return;
    int is64 = *flag;
    const int* rowp = eidx;
    const int* colp = eidx + ((size_t)E << is64);
    int r = ld_idx(rowp, e, is64);
    int c = ld_idx(colp, e, is64);
    const float4* up = (const float4*)(u + (size_t)r * HID);
    const float4* vp = (const float4*)(v + (size_t)c * HID);
    float l0 = b2s[0], l1 = b2s[1];
#pragma unroll
    for (int q = 0; q < 4; ++q) {
        float4 uu = up[q], vv = vp[q];
        float z;
        z = fmaxf(uu.x + vv.x + b1s[4 * q + 0], 0.f);
        l0 += z * W2s[(4 * q + 0) * 2 + 0]; l1 += z * W2s[(4 * q + 0) * 2 + 1];
        z = fmaxf(uu.y + vv.y + b1s[4 * q + 1], 0.f);
        l0 += z * W2s[(4 * q + 1) * 2 + 0]; l1 += z * W2s[(4 * q + 1) * 2 + 1];
        z = fmaxf(uu.z + vv.z + b1s[4 * q + 2], 0.f);
        l0 += z * W2s[(4 * q + 2) * 2 + 0]; l1 += z * W2s[(4 * q + 2) * 2 + 1];
        z = fmaxf(uu.w + vv.w + b1s[4 * q + 3], 0.f);
        l0 += z * W2s[(4 * q + 3) * 2 + 0]; l1 += z * W2s[(4 * q + 3) * 2 + 1];
    }
    float m = fmaxf(l0, l1);
    float e0 = __expf(l0 - m), e1 = __expf(l1 - m);
    float lse = m + __logf(e0 + e1);
    ((float2*)out)[e] = make_float2(l0 - lse, l1 - lse);
}

extern "C" void kernel_launch(void* const* d_in, const int* in_sizes, int n_in,
                              void* d_out, int out_size, void* d_ws, size_t ws_size,
                              hipStream_t stream) {
    const float* x    = (const float*)d_in[0];
    const int*   eidx = (const int*)d_in[1];
    const float* W1   = (const float*)d_in[2];
    const float* b1   = (const float*)d_in[3];
    const float* W2   = (const float*)d_in[4];
    const float* b2   = (const float*)d_in[5];
    const float* fc1W = (const float*)d_in[6];
    const float* fc1b = (const float*)d_in[7];
    const float* fc2W = (const float*)d_in[8];
    const float* fc2b = (const float*)d_in[9];

    const int n = in_sizes[0] / F_IN;   // 100000
    const int E = in_sizes[1] / 2;      // 3200000

    float* ws   = (float*)d_ws;
    float* dinv = ws;                          // [n]
    float* bufA = ws + n;                      // [n*16]  h / u
    float* bufB = bufA + (size_t)n * HID;      // [n*16]  agg / v
    float* bufC = bufB + (size_t)n * HID;      // [n*16]  hr
    int*   flag = (int*)(bufC + (size_t)n * HID);
    float* out  = (float*)d_out;

    k_detect<<<1, 64, 0, stream>>>(eidx, flag);

    hipMemsetAsync(dinv, 0, n * sizeof(float), stream);
    k_deg<<<(E + 255) / 256, 256, 0, stream>>>(eidx, E, flag, dinv);
    k_dinv<<<(n + 255) / 256, 256, 0, stream>>>(dinv, n);

    // layer 1
    k_gemm1<<<(n + 15) / 16, 256, 0, stream>>>(x, W1, bufA, n);
    hipMemsetAsync(bufB, 0, (size_t)n * HID * sizeof(float), stream);
    {
        long long total = (long long)E * HID;
        k_agg<<<(int)((total + 255) / 256), 256, 0, stream>>>(eidx, E, flag, bufA, dinv, bufB);
    }
    k_finish<<<(n * HID + 255) / 256, 256, 0, stream>>>(bufB, bufA, dinv, b1, bufC, n);

    // layer 2
    k_gemm2<<<(n + 15) / 16, 256, 0, stream>>>(bufC, W2, bufA, n);
    hipMemsetAsync(bufB, 0, (size_t)n * HID * sizeof(float), stream);
    {
        long long total = (long long)E * HID;
        k_agg<<<(int)((total + 255) / 256), 256, 0, stream>>>(eidx, E, flag, bufA, dinv, bufB);
    }
    k_finish<<<(n * HID + 255) / 256, 256, 0, stream>>>(bufB, bufA, dinv, b2, bufC, n);

    // edge MLP: u/v precompute then per-edge
    k_uv<<<(n + 15) / 16, 256, 0, stream>>>(bufC, fc1W, bufA, bufB, n);
    k_edge<<<(E + 255) / 256, 256, 0, stream>>>(eidx, E, flag, bufA, bufB,
                                                fc1b, fc2W, fc2b, out);
}